// Round 8
// baseline (1656.235 us; speedup 1.0000x reference)
//
#include <hip/hip_runtime.h>
#include <hip/hip_bf16.h>

// ---------------------------------------------------------------------------
// VQ-VAE pose: fused fp32 pipeline. Round 14:
//  - res_k: was 75.3KB LDS (Hr[64][260]+T1) -> 2 blocks/CU, 25% occupancy,
//    same inline-L2-load disease enc01 had. Round-13 recipe applied: raw H
//    staged in two 128-col halves into S[64][132] (relu at quad-read,
//    ds_read_b128, 2-way=free), mm1 accumulates across halves; mm2 residual
//    re-read from global H (block's own 64KB tile, L2-hot). LDS 42.5KB ->
//    3 blocks/CU. mm1 keeps round-8 thread map (8 fma : 4 load-floats).
//  - enc01_k (round-13) / gemmf_k (round-11) / vq_k / gemm_k(d2) untouched.
// ---------------------------------------------------------------------------

#define NTOT 131072            // B*T
#define EDIM 64
#define NEMB 512

// ---------------- dtype detection (fp32 vs bf16) ---------------------------
__global__ void detect_k(const void* __restrict__ x, int* __restrict__ flag,
                         float* __restrict__ acc)
{
    __shared__ int s_bad;
    if (threadIdx.x == 0) s_bad = 0;
    __syncthreads();
    const unsigned short* u = (const unsigned short*)x;
    int bad = 0;
    for (int i = threadIdx.x; i < 2048; i += 256) {
        unsigned short h = u[i];
        int ex = (h >> 7) & 0xFF;
        if (h != 0 && (ex < 100 || ex > 140)) bad++;
    }
    atomicAdd(&s_bad, bad);
    __syncthreads();
    if (threadIdx.x == 0) { *flag = (s_bad > 256) ? 1 : 0; *acc = 0.f; }
}

// -------- convert weights to fp32; 2-D weights transposed to K-major -------
struct WTbl { const void* p[31]; int off[31]; int n[31]; int Kd[31]; };

__global__ void convw_k(WTbl t, float* __restrict__ dst, const int* __restrict__ flag)
{
    const bool f32 = (*flag != 0);
    const int ti = blockIdx.x;
    const void* src = t.p[ti];
    float* d = dst + t.off[ti];
    const int n = t.n[ti];
    const int K = t.Kd[ti];
    if (K == 0) {
        for (int i = threadIdx.x; i < n; i += 256)
            d[i] = f32 ? ((const float*)src)[i]
                       : __bfloat162float(((const __hip_bfloat16*)src)[i]);
    } else {
        const int O = n / K;
        for (int j = threadIdx.x; j < n; j += 256) {
            int k = j / O, o = j - k * O;           // dst[k][o] = src[o][k]
            int si = o * K + k;
            d[j] = f32 ? ((const float*)src)[si]
                       : __bfloat162float(((const __hip_bfloat16*)src)[si]);
        }
    }
}

// ---------------- fused enc0+enc1: x[165] -> relu128 -> relu256 ------------
// X staged in two 84-col halves into S[64][132] (reused as H1) -> 33.8KB LDS
// -> 4 blocks/CU. k-quad ds_read_b128; W per-lane from L2 (no prefetch).
__global__ __launch_bounds__(256)
void enc01_k(const void* __restrict__ X,
             const float* __restrict__ W0t, const float* __restrict__ B0,  // [165][128],[128]
             const float* __restrict__ W1t, const float* __restrict__ B1,  // [128][256],[256]
             float* __restrict__ Y, const int* __restrict__ dtf)
{
    __shared__ float S[64][132];     // X half-tile (84 cols) / H1 (128 cols)

    const bool f32d = (*dtf != 0);
    const int tid = threadIdx.x;
    const int r0  = blockIdx.x * 64;

    const int tx = tid & 15;         // layer1: cols {tx*4..+3, 64+tx*4..+3}
    const int ty = tid >> 4;         // layer1: rows ty*4..+3

    // ---- layer 1: K=165 in two 84-col halves (pad zero); 4 rows x 8 cols --
    float acc1[4][8] = {};
    for (int h = 0; h < 2; ++h) {
        const int kb = h * 84;
        for (int e = tid; e < 64 * 84; e += 256) {
            int m = e / 84, k = e - m * 84;
            int kg = kb + k;
            float v = 0.f;
            if (kg < 165) {
                size_t gi = (size_t)(r0 + m) * 165 + kg;
                v = f32d ? ((const float*)X)[gi]
                         : __bfloat162float(((const __hip_bfloat16*)X)[gi]);
            }
            S[m][k] = v;
        }
        __syncthreads();

        for (int k4 = 0; k4 < 84; k4 += 4) {
            float a4[4][4];
            #pragma unroll
            for (int i = 0; i < 4; ++i)
                *(float4*)&a4[i][0] = *(const float4*)&S[ty * 4 + i][k4];
            const int kwb = kb + k4;
            #pragma unroll
            for (int kk = 0; kk < 4; ++kk) {
                float b[8];
                *(float4*)&b[0] = *(const float4*)(W0t + (size_t)(kwb + kk) * 128 + tx * 4);
                *(float4*)&b[4] = *(const float4*)(W0t + (size_t)(kwb + kk) * 128 + 64 + tx * 4);
                #pragma unroll
                for (int i = 0; i < 4; ++i)
                    #pragma unroll
                    for (int j = 0; j < 8; ++j)
                        acc1[i][j] = fmaf(a4[i][kk], b[j], acc1[i][j]);
            }
        }
        __syncthreads();             // half's X reads done before restage
    }

    // H1 = relu(acc1 + B0) into S (cols 0..127)
    {
        float bb[8];
        *(float4*)&bb[0] = *(const float4*)(B0 + tx * 4);
        *(float4*)&bb[4] = *(const float4*)(B0 + 64 + tx * 4);
        #pragma unroll
        for (int i = 0; i < 4; ++i) {
            float4 v0, v1;
            v0.x = fmaxf(acc1[i][0] + bb[0], 0.f);
            v0.y = fmaxf(acc1[i][1] + bb[1], 0.f);
            v0.z = fmaxf(acc1[i][2] + bb[2], 0.f);
            v0.w = fmaxf(acc1[i][3] + bb[3], 0.f);
            v1.x = fmaxf(acc1[i][4] + bb[4], 0.f);
            v1.y = fmaxf(acc1[i][5] + bb[5], 0.f);
            v1.z = fmaxf(acc1[i][6] + bb[6], 0.f);
            v1.w = fmaxf(acc1[i][7] + bb[7], 0.f);
            *(float4*)&S[ty * 4 + i][tx * 4]      = v0;
            *(float4*)&S[ty * 4 + i][64 + tx * 4] = v1;
        }
    }
    __syncthreads();

    // ---- layer 2: K=128, 256 cols; 8 rows x (4+4) cols per thread ----
    const int tx2 = tid & 31;        // cols {tx2*4..+3, 128+tx2*4..+3}
    const int ty2 = tid >> 5;        // rows ty2*8..+7
    float acc2[2][8][4] = {};
    for (int k4 = 0; k4 < 128; k4 += 4) {
        float a4[8][4];
        #pragma unroll
        for (int i = 0; i < 8; ++i)
            *(float4*)&a4[i][0] = *(const float4*)&S[ty2 * 8 + i][k4];
        #pragma unroll
        for (int kk = 0; kk < 4; ++kk) {
            float b0[4], b1[4];
            *(float4*)&b0[0] = *(const float4*)(W1t + (size_t)(k4 + kk) * 256 + tx2 * 4);
            *(float4*)&b1[0] = *(const float4*)(W1t + (size_t)(k4 + kk) * 256 + 128 + tx2 * 4);
            #pragma unroll
            for (int i = 0; i < 8; ++i)
                #pragma unroll
                for (int j = 0; j < 4; ++j) {
                    acc2[0][i][j] = fmaf(a4[i][kk], b0[j], acc2[0][i][j]);
                    acc2[1][i][j] = fmaf(a4[i][kk], b1[j], acc2[1][i][j]);
                }
        }
    }
    {
        float bb0[4], bb1[4];
        *(float4*)&bb0[0] = *(const float4*)(B1 + tx2 * 4);
        *(float4*)&bb1[0] = *(const float4*)(B1 + 128 + tx2 * 4);
        #pragma unroll
        for (int i = 0; i < 8; ++i) {
            const size_t row = (size_t)(r0 + ty2 * 8 + i) * 256;
            float4 v0, v1;
            v0.x = fmaxf(acc2[0][i][0] + bb0[0], 0.f);
            v0.y = fmaxf(acc2[0][i][1] + bb0[1], 0.f);
            v0.z = fmaxf(acc2[0][i][2] + bb0[2], 0.f);
            v0.w = fmaxf(acc2[0][i][3] + bb0[3], 0.f);
            v1.x = fmaxf(acc2[1][i][0] + bb1[0], 0.f);
            v1.y = fmaxf(acc2[1][i][1] + bb1[1], 0.f);
            v1.z = fmaxf(acc2[1][i][2] + bb1[2], 0.f);
            v1.w = fmaxf(acc2[1][i][3] + bb1[3], 0.f);
            *(float4*)(Y + row + tx2 * 4)       = v0;
            *(float4*)(Y + row + 128 + tx2 * 4) = v1;
        }
    }
}

// ---------------- fused resblock: h += W1 @ relu(W0 @ relu(h)) -------------
// Raw H staged in two 128-col halves (S[64][132], 33.8KB); mm1 accumulates
// across halves with relu at quad-read; mm2 residual re-read from global H
// (block's own tile, L2-hot). Total LDS 42.5KB -> 3 blocks/CU.
__global__ __launch_bounds__(256)
void res_k(float* __restrict__ H,
           const float* __restrict__ W0t, const float* __restrict__ B0,  // [256][32],[32]
           const float* __restrict__ W1t, const float* __restrict__ B1)  // [32][256],[256]
{
    __shared__ float S[64][132];     // raw H half-tile (128 cols)
    __shared__ float T1[32][68];     // mid activations, k-major [midcol][row]

    const int tid = threadIdx.x;
    const int r0  = blockIdx.x * 64;

    // mm1: 64 rows x 32 cols, K=256 in two halves; 2 rows x 4 cols per thread
    const int tx1 = tid & 7;
    const int ty1 = tid >> 3;
    float acc1[2][4] = {};

    for (int h = 0; h < 2; ++h) {
        const int kb = h * 128;
        // stage 64 x 128 half: coalesced float4
        #pragma unroll
        for (int it = 0; it < 8; ++it) {
            int idx = tid + it * 256;            // 64 rows x 32 float4
            int q = idx & 31, m = idx >> 5;
            float4 v = *(const float4*)(H + (size_t)(r0 + m) * 256 + kb + q * 4);
            *(float4*)&S[m][q * 4] = v;
        }
        __syncthreads();

        for (int k4 = 0; k4 < 128; k4 += 4) {
            float a0[4], a1[4];
            *(float4*)&a0[0] = *(const float4*)&S[ty1 * 2][k4];
            *(float4*)&a1[0] = *(const float4*)&S[ty1 * 2 + 1][k4];
            #pragma unroll
            for (int q = 0; q < 4; ++q) {
                a0[q] = fmaxf(a0[q], 0.f);
                a1[q] = fmaxf(a1[q], 0.f);
            }
            const int kw = kb + k4;
            #pragma unroll
            for (int kk = 0; kk < 4; ++kk) {
                float b[4];
                *(float4*)&b[0] = *(const float4*)(W0t + (size_t)(kw + kk) * 32 + tx1 * 4);
                #pragma unroll
                for (int j = 0; j < 4; ++j) {
                    acc1[0][j] = fmaf(a0[kk], b[j], acc1[0][j]);
                    acc1[1][j] = fmaf(a1[kk], b[j], acc1[1][j]);
                }
            }
        }
        __syncthreads();             // half's reads done before restage
    }

    {
        float bb[4];
        *(float4*)&bb[0] = *(const float4*)(B0 + tx1 * 4);
        #pragma unroll
        for (int i = 0; i < 2; ++i)
            #pragma unroll
            for (int j = 0; j < 4; ++j)
                T1[tx1 * 4 + j][ty1 * 2 + i] = fmaxf(acc1[i][j] + bb[j], 0.f);
    }
    __syncthreads();

    // mm2: 64 rows x 256 cols, K=32; 8 rows x (4+4) cols per thread;
    // residual read from global H (L2-hot own tile).
    const int tx2 = tid & 31;
    const int ty2 = tid >> 5;
    float acc2[2][8][4] = {};
    #pragma unroll 8
    for (int k = 0; k < 32; ++k) {
        float b0[4], b1[4], a[8];
        *(float4*)&b0[0] = *(const float4*)(W1t + (size_t)k * 256 + tx2 * 4);
        *(float4*)&b1[0] = *(const float4*)(W1t + (size_t)k * 256 + 128 + tx2 * 4);
        *(float4*)&a[0] = *(const float4*)&T1[k][ty2 * 8];
        *(float4*)&a[4] = *(const float4*)&T1[k][ty2 * 8 + 4];
        #pragma unroll
        for (int i = 0; i < 8; ++i)
            #pragma unroll
            for (int j = 0; j < 4; ++j) {
                acc2[0][i][j] = fmaf(a[i], b0[j], acc2[0][i][j]);
                acc2[1][i][j] = fmaf(a[i], b1[j], acc2[1][i][j]);
            }
    }
    {
        float bb0[4], bb1[4];
        *(float4*)&bb0[0] = *(const float4*)(B1 + tx2 * 4);
        *(float4*)&bb1[0] = *(const float4*)(B1 + 128 + tx2 * 4);
        #pragma unroll
        for (int i = 0; i < 8; ++i) {
            const int row = ty2 * 8 + i;
            const size_t gr = (size_t)(r0 + row) * 256;
            float4 h0 = *(const float4*)(H + gr + tx2 * 4);
            float4 h1 = *(const float4*)(H + gr + 128 + tx2 * 4);
            float4 v0, v1;
            v0.x = h0.x + acc2[0][i][0] + bb0[0];
            v0.y = h0.y + acc2[0][i][1] + bb0[1];
            v0.z = h0.z + acc2[0][i][2] + bb0[2];
            v0.w = h0.w + acc2[0][i][3] + bb0[3];
            v1.x = h1.x + acc2[1][i][0] + bb1[0];
            v1.y = h1.y + acc2[1][i][1] + bb1[1];
            v1.z = h1.z + acc2[1][i][2] + bb1[2];
            v1.w = h1.w + acc2[1][i][3] + bb1[3];
            *(float4*)(H + gr + tx2 * 4)       = v0;
            *(float4*)(H + gr + 128 + tx2 * 4) = v1;
        }
    }
}

// ---------------- full-width GEMM, W register-prefetch pipeline ------------
template <int K, int OC, bool PRE_RELU, bool POST_RELU>
__global__ __launch_bounds__(256)
void gemmf_k(const float* __restrict__ X, const float* __restrict__ Wt,
             const float* __restrict__ Bv, float* __restrict__ Y)
{
    constexpr int KH  = (K < 128) ? K : 128;      // staged K-half
    constexpr int SW  = KH + 4;                   // padded row stride (16B-aligned)
    constexpr int TX  = (OC == 256) ? 32 : 16;
    constexpr int TYN = 256 / TX;                 // # ty groups
    constexpr int RP  = 64 / TYN;                 // rows per thread
    constexpr int NCH = (OC > TX * 4) ? 2 : 1;    // col chunks
    constexpr int CHW = OC / NCH;                 // chunk width

    __shared__ float S[64 * SW];

    const int tid = threadIdx.x;
    const int r0  = blockIdx.x * 64;
    const int tx  = tid & (TX - 1);
    const int ty  = tid / TX;

    float acc[NCH][RP][4] = {};
    float4 bA[4][NCH], bB[4][NCH];

#define LOADW(dst, kb)                                                        \
    {                                                                         \
        _Pragma("unroll")                                                     \
        for (int kk = 0; kk < 4; ++kk)                                        \
            _Pragma("unroll")                                                 \
            for (int c = 0; c < NCH; ++c)                                     \
                dst[kk][c] = *(const float4*)(Wt + (size_t)((kb) + kk) * OC   \
                                              + c * CHW + tx * 4);            \
    }

#define COMPQ(bsrc, kl)                                                       \
    {                                                                         \
        float a4[RP][4];                                                      \
        _Pragma("unroll")                                                     \
        for (int i = 0; i < RP; ++i)                                          \
            *(float4*)&a4[i][0] = *(const float4*)&S[(ty * RP + i) * SW + (kl)]; \
        _Pragma("unroll")                                                     \
        for (int kk = 0; kk < 4; ++kk)                                        \
            _Pragma("unroll")                                                 \
            for (int c = 0; c < NCH; ++c) {                                   \
                const float* bp = (const float*)&bsrc[kk][c];                 \
                _Pragma("unroll")                                             \
                for (int i = 0; i < RP; ++i)                                  \
                    _Pragma("unroll")                                         \
                    for (int j = 0; j < 4; ++j)                               \
                        acc[c][i][j] = fmaf(a4[i][kk], bp[j], acc[c][i][j]);  \
            }                                                                 \
    }

    LOADW(bA, 0);                                 // prologue: first quad

    for (int h = 0; h < K; h += KH) {
        // stage 64 x KH (coalesced float4; optional relu)
        #pragma unroll
        for (int it = 0; it < (64 * KH / 4) / 256; ++it) {
            int idx = tid + it * 256;
            int m = idx / (KH / 4), g = idx % (KH / 4);
            float4 v = *(const float4*)(X + (size_t)(r0 + m) * K + h + g * 4);
            if (PRE_RELU) {
                v.x = fmaxf(v.x, 0.f); v.y = fmaxf(v.y, 0.f);
                v.z = fmaxf(v.z, 0.f); v.w = fmaxf(v.w, 0.f);
            }
            *(float4*)&S[m * SW + g * 4] = v;
        }
        __syncthreads();

        for (int k8 = 0; k8 < KH; k8 += 8) {
            LOADW(bB, h + k8 + 4);                // prefetch quad 2
            COMPQ(bA, k8);
            const int kn = (h + k8 + 8 < K) ? (h + k8 + 8) : 0;  // next quad (or dummy)
            LOADW(bA, kn);                        // prefetch quad 1 of next pair/half
            COMPQ(bB, k8 + 4);
        }
        __syncthreads();
    }
#undef LOADW
#undef COMPQ

    #pragma unroll
    for (int c = 0; c < NCH; ++c) {
        float bb[4];
        *(float4*)&bb[0] = *(const float4*)(Bv + c * CHW + tx * 4);
        #pragma unroll
        for (int i = 0; i < RP; ++i) {
            float4 v;
            v.x = acc[c][i][0] + bb[0];
            v.y = acc[c][i][1] + bb[1];
            v.z = acc[c][i][2] + bb[2];
            v.w = acc[c][i][3] + bb[3];
            if (POST_RELU) {
                v.x = fmaxf(v.x, 0.f); v.y = fmaxf(v.y, 0.f);
                v.z = fmaxf(v.z, 0.f); v.w = fmaxf(v.w, 0.f);
            }
            *(float4*)(Y + (size_t)(r0 + ty * RP + i) * OC + c * CHW + tx * 4) = v;
        }
    }
}

// ---------------- standalone GEMM (used only for d2, O=165) ---------------
template <bool PRE_RELU, bool POST_RELU, int YM>
__global__ __launch_bounds__(256)
void gemm_k(const float* __restrict__ X, const float* __restrict__ Wt,
            const float* __restrict__ Bv, void* __restrict__ Y,
            int K, int O, const int* __restrict__ dtf)
{
    __shared__ float Xs[32][132];
    __shared__ float Ws[32][68];

    const bool f32d = (YM == 1) ? (*dtf != 0) : false;
    const int tid = threadIdx.x;
    const int tx  = tid & 15;
    const int ty  = tid >> 4;
    const int o0  = blockIdx.x * 64;
    const int m0  = blockIdx.y * 128;

    float acc[8][4] = {};
    const int KC = K >> 5;                       // K multiple of 32
    for (int kc = 0; kc < KC; ++kc) {
        const int k0 = kc << 5;
        #pragma unroll
        for (int it = 0; it < 4; ++it) {         // X: 128 x 32 as float4
            int idx = tid + it * 256;
            int kq = idx & 7, m = idx >> 3;
            float4 v = *(const float4*)(X + (size_t)(m0 + m) * K + k0 + kq * 4);
            if (PRE_RELU) {
                v.x = fmaxf(v.x, 0.f); v.y = fmaxf(v.y, 0.f);
                v.z = fmaxf(v.z, 0.f); v.w = fmaxf(v.w, 0.f);
            }
            Xs[kq * 4 + 0][m] = v.x; Xs[kq * 4 + 1][m] = v.y;
            Xs[kq * 4 + 2][m] = v.z; Xs[kq * 4 + 3][m] = v.w;
        }
        #pragma unroll
        for (int it = 0; it < 8; ++it) {
            int e = tid + it * 256;
            int kk = e & 31, o = e >> 5;
            int og = o0 + o;
            Ws[kk][o] = (og < O) ? Wt[(size_t)(k0 + kk) * O + og] : 0.f;
        }
        __syncthreads();
        #pragma unroll
        for (int kk = 0; kk < 32; ++kk) {
            float a[8], b[4];
            *(float4*)&a[0] = *(const float4*)&Xs[kk][ty * 8];
            *(float4*)&a[4] = *(const float4*)&Xs[kk][ty * 8 + 4];
            *(float4*)&b[0] = *(const float4*)&Ws[kk][tx * 4];
            #pragma unroll
            for (int i = 0; i < 8; ++i)
                #pragma unroll
                for (int j = 0; j < 4; ++j)
                    acc[i][j] = fmaf(a[i], b[j], acc[i][j]);
        }
        __syncthreads();
    }

    #pragma unroll
    for (int j = 0; j < 4; ++j) {
        int c = o0 + tx * 4 + j;
        if (c >= O) continue;
        float bb = Bv[c];
        #pragma unroll
        for (int i = 0; i < 8; ++i) {
            int r = m0 + ty * 8 + i;
            float v = acc[i][j] + bb;
            if (POST_RELU) v = fmaxf(v, 0.f);
            size_t yi = (size_t)r * O + c;
            if (YM == 0)   ((float*)Y)[yi] = v;
            else if (f32d) ((float*)Y)[yi] = v;
            else           ((__hip_bfloat16*)Y)[yi] = __float2bfloat16(v);
        }
    }
}

// ---------------- codebook prep --------------------------------------------
__global__ void prep_k(const float* __restrict__ E, float* __restrict__ Et)
{
    int idx = blockIdx.x * 256 + threadIdx.x;   // E is [64][512]
    Et[(idx & 511) * EDIM + (idx >> 9)] = E[idx];
}

__global__ void e2_k(const float* __restrict__ Et, float* __restrict__ e2)
{
    int e = blockIdx.x * 256 + threadIdx.x;
    float s = 0.f;
    #pragma unroll
    for (int d = 0; d < EDIM; ++d) { float v = Et[e * EDIM + d]; s = fmaf(v, v, s); }
    e2[e] = s;
}

// ---------------- VQ as tiled GEMM-argmin ----------------------------------
__global__ __launch_bounds__(256)
void vq_k(float* __restrict__ Zq, const float* __restrict__ Ed,
          const float* __restrict__ Et, const float* __restrict__ e2,
          float* __restrict__ acc)
{
    __shared__ float Zs[64][132];    // [d][row], 128 rows + pad
    __shared__ float Es[64][68];     // [d][code] chunk of 64 codes

    const int tid = threadIdx.x;
    const int tx  = tid & 15;        // code group (4 codes)
    const int ty  = tid >> 4;        // row group (8 rows)
    const int r0  = blockIdx.x * 128;

    // stage Z tile k-major
    #pragma unroll
    for (int it = 0; it < 8; ++it) {
        int idx = tid + it * 256;                // 128 rows x 16 float4
        int dq = idx & 15, m = idx >> 4;
        float4 v = *(const float4*)(Zq + (size_t)(r0 + m) * 64 + dq * 4);
        Zs[dq * 4 + 0][m] = v.x; Zs[dq * 4 + 1][m] = v.y;
        Zs[dq * 4 + 2][m] = v.z; Zs[dq * 4 + 3][m] = v.w;
    }

    float best[8];
    int   bi[8];
    #pragma unroll
    for (int i = 0; i < 8; ++i) { best[i] = 3.4e38f; bi[i] = 0; }

    for (int cc = 0; cc < 8; ++cc) {
        const int c0 = cc * 64;
        #pragma unroll
        for (int it = 0; it < 4; ++it) {
            int idx = tid + it * 256;            // 64 k x 16 float4
            int oq = idx & 15, kk = idx >> 4;
            *(float4*)&Es[kk][oq * 4] =
                *(const float4*)(Ed + (size_t)kk * NEMB + c0 + oq * 4);
        }
        float4 e2v = *(const float4*)(e2 + c0 + tx * 4);
        __syncthreads();

        float a4[8][4] = {};
        #pragma unroll 8
        for (int kk = 0; kk < 64; ++kk) {
            float a[8], b[4];
            *(float4*)&a[0] = *(const float4*)&Zs[kk][ty * 8];
            *(float4*)&a[4] = *(const float4*)&Zs[kk][ty * 8 + 4];
            *(float4*)&b[0] = *(const float4*)&Es[kk][tx * 4];
            #pragma unroll
            for (int i = 0; i < 8; ++i)
                #pragma unroll
                for (int j = 0; j < 4; ++j)
                    a4[i][j] = fmaf(a[i], b[j], a4[i][j]);
        }

        const float e2a[4] = {e2v.x, e2v.y, e2v.z, e2v.w};
        #pragma unroll
        for (int j = 0; j < 4; ++j) {
            const int code = c0 + tx * 4 + j;    // visited in increasing order
            #pragma unroll
            for (int i = 0; i < 8; ++i) {
                float s = fmaf(-2.f, a4[i][j], e2a[j]);
                if (s < best[i]) { best[i] = s; bi[i] = code; }  // strict <: first-min
            }
        }
        __syncthreads();
    }

    // argmin reduce over the 16 lanes sharing each row (tie-break low index)
    #pragma unroll
    for (int i = 0; i < 8; ++i) {
        #pragma unroll
        for (int m = 1; m < 16; m <<= 1) {
            float ob = __shfl_xor(best[i], m);
            int   oi = __shfl_xor(bi[i], m);
            if (ob < best[i] || (ob == best[i] && oi < bi[i])) {
                best[i] = ob; bi[i] = oi;
            }
        }
    }

    // gather winner rows, straight-through write in place, accumulate diff
    float ds = 0.f;
    #pragma unroll
    for (int i = 0; i < 8; ++i) {
        const int row = r0 + ty * 8 + i;
        float4 qv = *(const float4*)(Et + (size_t)bi[i] * 64 + tx * 4);
        float* zp = Zq + (size_t)row * 64 + tx * 4;
        float4 zv = *(const float4*)zp;
        float t;
        t = qv.x - zv.x; ds = fmaf(t, t, ds);
        t = qv.y - zv.y; ds = fmaf(t, t, ds);
        t = qv.z - zv.z; ds = fmaf(t, t, ds);
        t = qv.w - zv.w; ds = fmaf(t, t, ds);
        *(float4*)zp = qv;
    }
    #pragma unroll
    for (int off = 32; off; off >>= 1) ds += __shfl_down(ds, off);
    if ((tid & 63) == 0) atomicAdd(acc, ds);
}

__global__ void diff_k(const float* __restrict__ acc, void* __restrict__ out,
                       size_t off, const int* __restrict__ dtf)
{
    if (threadIdx.x == 0) {
        float v = *acc * (1.0f / 8388608.0f);
        if (*dtf) ((float*)out)[off] = v;
        else      ((__hip_bfloat16*)out)[off] = __float2bfloat16(v);
    }
}

// ---------------------------------------------------------------------------
extern "C" void kernel_launch(void* const* d_in, const int* in_sizes, int n_in,
                              void* d_out, int out_size, void* d_ws, size_t ws_size,
                              hipStream_t stream)
{
    const size_t MB = 1048576;
    char* ws = (char*)d_ws;
    float* Zq  = (float*)ws;                                  // N x 64
    float* A1  = (float*)(ws + 32 * MB);                      // N x 256
    float* A2  = (float*)(ws + 32 * MB + 128 * MB);           // N x 256
    float* Wf  = (float*)(ws + 288 * MB);                     // fp32 weights
    float* Et  = (float*)(ws + 288 * MB + 1310720);           // 512 x 64
    float* e2  = Et + NEMB * EDIM;
    float* acc = e2 + NEMB;
    int*   dtf = (int*)(acc + 1);

    // weight table (K-major transpose for 2-D weights)
    static const int KDIM[32] = {0, 165,0, 128,0, 256,0, 256,0, 32,0, 256,0, 32,0,
                                 256,0, 0, 64,0, 256,0, 32,0, 256,0, 32,0, 256,0, 128,0};
    WTbl t;
    int off[32];
    int cum = 0;
    for (int i = 1; i < 32; ++i) {
        t.p[i - 1]   = d_in[i];
        t.off[i - 1] = cum;
        t.n[i - 1]   = in_sizes[i];
        t.Kd[i - 1]  = KDIM[i];
        off[i] = cum;
        cum += in_sizes[i];
    }
    const float* W_ew0 = Wf + off[1],  *B_ew0 = Wf + off[2];
    const float* W_ew1 = Wf + off[3],  *B_ew1 = Wf + off[4];
    const float* W_ew2 = Wf + off[5],  *B_ew2 = Wf + off[6];
    const float* W_r0a = Wf + off[7],  *B_r0a = Wf + off[8];
    const float* W_r0b = Wf + off[9],  *B_r0b = Wf + off[10];
    const float* W_r1a = Wf + off[11], *B_r1a = Wf + off[12];
    const float* W_r1b = Wf + off[13], *B_r1b = Wf + off[14];
    const float* W_qc  = Wf + off[15], *B_qc  = Wf + off[16];
    const float* Emb   = Wf + off[17];
    const float* W_d0  = Wf + off[18], *B_d0  = Wf + off[19];
    const float* W_s0a = Wf + off[20], *B_s0a = Wf + off[21];
    const float* W_s0b = Wf + off[22], *B_s0b = Wf + off[23];
    const float* W_s1a = Wf + off[24], *B_s1a = Wf + off[25];
    const float* W_s1b = Wf + off[26], *B_s1b = Wf + off[27];
    const float* W_d1  = Wf + off[28], *B_d1  = Wf + off[29];
    const float* W_d2  = Wf + off[30], *B_d2  = Wf + off[31];

    dim3 blk(256);
    const int NB = NTOT / 64;          // 2048 row blocks

    detect_k<<<1, blk, 0, stream>>>(d_in[0], dtf, acc);
    convw_k<<<31, blk, 0, stream>>>(t, Wf, dtf);
    prep_k<<<128, blk, 0, stream>>>(Emb, Et);
    e2_k<<<2, blk, 0, stream>>>(Et, e2);

    // ---- encoder ----
    enc01_k<<<NB, blk, 0, stream>>>(d_in[0], W_ew0, B_ew0, W_ew1, B_ew1, A1, dtf);
    gemmf_k<256, 256, false, false><<<NB, blk, 0, stream>>>(A1, W_ew2, B_ew2, A2);
    res_k<<<NB, blk, 0, stream>>>(A2, W_r0a, B_r0a, W_r0b, B_r0b);
    res_k<<<NB, blk, 0, stream>>>(A2, W_r1a, B_r1a, W_r1b, B_r1b);
    gemmf_k<256, 64, true, false><<<NB, blk, 0, stream>>>(A2, W_qc, B_qc, Zq);

    // ---- VQ (in place, GEMM-argmin) ----
    vq_k<<<NTOT / 128, blk, 0, stream>>>(Zq, Emb, Et, e2, acc);

    // ---- decoder ----
    gemmf_k<64, 256, false, false><<<NB, blk, 0, stream>>>(Zq, W_d0, B_d0, A1);
    res_k<<<NB, blk, 0, stream>>>(A1, W_s0a, B_s0a, W_s0b, B_s0b);
    res_k<<<NB, blk, 0, stream>>>(A1, W_s1a, B_s1a, W_s1b, B_s1b);
    gemmf_k<256, 128, true, true><<<NB, blk, 0, stream>>>(A1, W_d1, B_d1, A2);
    gemm_k<false, false, 1><<<dim3(3, NTOT / 128), blk, 0, stream>>>
        (A2, W_d2, B_d2, d_out, 128, 165, dtf);

    diff_k<<<1, 64, 0, stream>>>(acc, d_out, (size_t)NTOT * 165, dtf);
}

// Round 9
// 1621.666 us; speedup vs baseline: 1.0213x; 1.0213x over previous
//
#include <hip/hip_runtime.h>
#include <hip/hip_bf16.h>

// ---------------------------------------------------------------------------
// VQ-VAE pose: fused fp32 pipeline. Round 15:
//  - res_k REVERTED to round-8 body (round-14 two-half restage regressed
//    +30us: extra barriers + global residual re-read cost more than the
//    2->3 blocks/CU gain).
//  - ALGEBRAIC: decoder-conv0 input rows are exactly codebook rows
//    (straight-through: forward value == quant == Et[ind]). d0 output takes
//    only 512 distinct values -> precompute D0tab[512][256] = Et@W_d0^T + b
//    (d0tab_k, ~5us, L2-resident), vq_k gathers D0tab[bi] straight into A1
//    (no Zq writeback), and the gemmf<64,256> d0 dispatch is DELETED.
//  - enc01_k (round-13) / gemmf_k (round-11) / gemm_k(d2) untouched.
// ---------------------------------------------------------------------------

#define NTOT 131072            // B*T
#define EDIM 64
#define NEMB 512

// ---------------- dtype detection (fp32 vs bf16) ---------------------------
__global__ void detect_k(const void* __restrict__ x, int* __restrict__ flag,
                         float* __restrict__ acc)
{
    __shared__ int s_bad;
    if (threadIdx.x == 0) s_bad = 0;
    __syncthreads();
    const unsigned short* u = (const unsigned short*)x;
    int bad = 0;
    for (int i = threadIdx.x; i < 2048; i += 256) {
        unsigned short h = u[i];
        int ex = (h >> 7) & 0xFF;
        if (h != 0 && (ex < 100 || ex > 140)) bad++;
    }
    atomicAdd(&s_bad, bad);
    __syncthreads();
    if (threadIdx.x == 0) { *flag = (s_bad > 256) ? 1 : 0; *acc = 0.f; }
}

// -------- convert weights to fp32; 2-D weights transposed to K-major -------
struct WTbl { const void* p[31]; int off[31]; int n[31]; int Kd[31]; };

__global__ void convw_k(WTbl t, float* __restrict__ dst, const int* __restrict__ flag)
{
    const bool f32 = (*flag != 0);
    const int ti = blockIdx.x;
    const void* src = t.p[ti];
    float* d = dst + t.off[ti];
    const int n = t.n[ti];
    const int K = t.Kd[ti];
    if (K == 0) {
        for (int i = threadIdx.x; i < n; i += 256)
            d[i] = f32 ? ((const float*)src)[i]
                       : __bfloat162float(((const __hip_bfloat16*)src)[i]);
    } else {
        const int O = n / K;
        for (int j = threadIdx.x; j < n; j += 256) {
            int k = j / O, o = j - k * O;           // dst[k][o] = src[o][k]
            int si = o * K + k;
            d[j] = f32 ? ((const float*)src)[si]
                       : __bfloat162float(((const __hip_bfloat16*)src)[si]);
        }
    }
}

// ---------------- fused enc0+enc1: x[165] -> relu128 -> relu256 ------------
// X staged in two 84-col halves into S[64][132] (reused as H1) -> 33.8KB LDS
// -> 4 blocks/CU. k-quad ds_read_b128; W per-lane from L2.
__global__ __launch_bounds__(256)
void enc01_k(const void* __restrict__ X,
             const float* __restrict__ W0t, const float* __restrict__ B0,  // [165][128],[128]
             const float* __restrict__ W1t, const float* __restrict__ B1,  // [128][256],[256]
             float* __restrict__ Y, const int* __restrict__ dtf)
{
    __shared__ float S[64][132];     // X half-tile (84 cols) / H1 (128 cols)

    const bool f32d = (*dtf != 0);
    const int tid = threadIdx.x;
    const int r0  = blockIdx.x * 64;

    const int tx = tid & 15;         // layer1: cols {tx*4..+3, 64+tx*4..+3}
    const int ty = tid >> 4;         // layer1: rows ty*4..+3

    // ---- layer 1: K=165 in two 84-col halves (pad zero); 4 rows x 8 cols --
    float acc1[4][8] = {};
    for (int h = 0; h < 2; ++h) {
        const int kb = h * 84;
        for (int e = tid; e < 64 * 84; e += 256) {
            int m = e / 84, k = e - m * 84;
            int kg = kb + k;
            float v = 0.f;
            if (kg < 165) {
                size_t gi = (size_t)(r0 + m) * 165 + kg;
                v = f32d ? ((const float*)X)[gi]
                         : __bfloat162float(((const __hip_bfloat16*)X)[gi]);
            }
            S[m][k] = v;
        }
        __syncthreads();

        for (int k4 = 0; k4 < 84; k4 += 4) {
            float a4[4][4];
            #pragma unroll
            for (int i = 0; i < 4; ++i)
                *(float4*)&a4[i][0] = *(const float4*)&S[ty * 4 + i][k4];
            const int kwb = kb + k4;
            #pragma unroll
            for (int kk = 0; kk < 4; ++kk) {
                float b[8];
                *(float4*)&b[0] = *(const float4*)(W0t + (size_t)(kwb + kk) * 128 + tx * 4);
                *(float4*)&b[4] = *(const float4*)(W0t + (size_t)(kwb + kk) * 128 + 64 + tx * 4);
                #pragma unroll
                for (int i = 0; i < 4; ++i)
                    #pragma unroll
                    for (int j = 0; j < 8; ++j)
                        acc1[i][j] = fmaf(a4[i][kk], b[j], acc1[i][j]);
            }
        }
        __syncthreads();             // half's X reads done before restage
    }

    // H1 = relu(acc1 + B0) into S (cols 0..127)
    {
        float bb[8];
        *(float4*)&bb[0] = *(const float4*)(B0 + tx * 4);
        *(float4*)&bb[4] = *(const float4*)(B0 + 64 + tx * 4);
        #pragma unroll
        for (int i = 0; i < 4; ++i) {
            float4 v0, v1;
            v0.x = fmaxf(acc1[i][0] + bb[0], 0.f);
            v0.y = fmaxf(acc1[i][1] + bb[1], 0.f);
            v0.z = fmaxf(acc1[i][2] + bb[2], 0.f);
            v0.w = fmaxf(acc1[i][3] + bb[3], 0.f);
            v1.x = fmaxf(acc1[i][4] + bb[4], 0.f);
            v1.y = fmaxf(acc1[i][5] + bb[5], 0.f);
            v1.z = fmaxf(acc1[i][6] + bb[6], 0.f);
            v1.w = fmaxf(acc1[i][7] + bb[7], 0.f);
            *(float4*)&S[ty * 4 + i][tx * 4]      = v0;
            *(float4*)&S[ty * 4 + i][64 + tx * 4] = v1;
        }
    }
    __syncthreads();

    // ---- layer 2: K=128, 256 cols; 8 rows x (4+4) cols per thread ----
    const int tx2 = tid & 31;        // cols {tx2*4..+3, 128+tx2*4..+3}
    const int ty2 = tid >> 5;        // rows ty2*8..+7
    float acc2[2][8][4] = {};
    for (int k4 = 0; k4 < 128; k4 += 4) {
        float a4[8][4];
        #pragma unroll
        for (int i = 0; i < 8; ++i)
            *(float4*)&a4[i][0] = *(const float4*)&S[ty2 * 8 + i][k4];
        #pragma unroll
        for (int kk = 0; kk < 4; ++kk) {
            float b0[4], b1[4];
            *(float4*)&b0[0] = *(const float4*)(W1t + (size_t)(k4 + kk) * 256 + tx2 * 4);
            *(float4*)&b1[0] = *(const float4*)(W1t + (size_t)(k4 + kk) * 256 + 128 + tx2 * 4);
            #pragma unroll
            for (int i = 0; i < 8; ++i)
                #pragma unroll
                for (int j = 0; j < 4; ++j) {
                    acc2[0][i][j] = fmaf(a4[i][kk], b0[j], acc2[0][i][j]);
                    acc2[1][i][j] = fmaf(a4[i][kk], b1[j], acc2[1][i][j]);
                }
        }
    }
    {
        float bb0[4], bb1[4];
        *(float4*)&bb0[0] = *(const float4*)(B1 + tx2 * 4);
        *(float4*)&bb1[0] = *(const float4*)(B1 + 128 + tx2 * 4);
        #pragma unroll
        for (int i = 0; i < 8; ++i) {
            const size_t row = (size_t)(r0 + ty2 * 8 + i) * 256;
            float4 v0, v1;
            v0.x = fmaxf(acc2[0][i][0] + bb0[0], 0.f);
            v0.y = fmaxf(acc2[0][i][1] + bb0[1], 0.f);
            v0.z = fmaxf(acc2[0][i][2] + bb0[2], 0.f);
            v0.w = fmaxf(acc2[0][i][3] + bb0[3], 0.f);
            v1.x = fmaxf(acc2[1][i][0] + bb1[0], 0.f);
            v1.y = fmaxf(acc2[1][i][1] + bb1[1], 0.f);
            v1.z = fmaxf(acc2[1][i][2] + bb1[2], 0.f);
            v1.w = fmaxf(acc2[1][i][3] + bb1[3], 0.f);
            *(float4*)(Y + row + tx2 * 4)       = v0;
            *(float4*)(Y + row + 128 + tx2 * 4) = v1;
        }
    }
}

// ---------------- fused resblock: h += W1 @ relu(W0 @ relu(h)) -------------
// Round-8 body (known-good, matches the 1626us best config).
__global__ __launch_bounds__(256)
void res_k(float* __restrict__ H,
           const float* __restrict__ W0t, const float* __restrict__ B0,  // [256][32],[32]
           const float* __restrict__ W1t, const float* __restrict__ B1)  // [32][256],[256]
{
    __shared__ float Hr[64][260];    // raw H tile (pre-relu), row-major
    __shared__ float T1[32][68];     // mid activations, k-major [midcol][row]

    const int tid = threadIdx.x;
    const int r0  = blockIdx.x * 64;

    // stage raw H tile: coalesced float4
    #pragma unroll
    for (int it = 0; it < 16; ++it) {
        int idx = tid + it * 256;                // 64 rows x 64 float4
        int q = idx & 63, m = idx >> 6;
        float4 v = *(const float4*)(H + (size_t)(r0 + m) * 256 + q * 4);
        *(float4*)&Hr[m][q * 4] = v;
    }
    __syncthreads();

    // mm1: 64 rows x 32 cols, K=256; tx1=tid&7 (4 cols), ty1=tid>>3 (2 rows)
    const int tx1 = tid & 7;
    const int ty1 = tid >> 3;
    float acc1[2][4] = {};
    #pragma unroll 8
    for (int k = 0; k < 256; ++k) {
        float b[4];
        *(float4*)&b[0] = *(const float4*)(W0t + (size_t)k * 32 + tx1 * 4);
        float a0 = fmaxf(Hr[ty1 * 2][k], 0.f);
        float a1 = fmaxf(Hr[ty1 * 2 + 1][k], 0.f);
        #pragma unroll
        for (int j = 0; j < 4; ++j) {
            acc1[0][j] = fmaf(a0, b[j], acc1[0][j]);
            acc1[1][j] = fmaf(a1, b[j], acc1[1][j]);
        }
    }
    {
        float bb[4];
        *(float4*)&bb[0] = *(const float4*)(B0 + tx1 * 4);
        #pragma unroll
        for (int i = 0; i < 2; ++i)
            #pragma unroll
            for (int j = 0; j < 4; ++j)
                T1[tx1 * 4 + j][ty1 * 2 + i] = fmaxf(acc1[i][j] + bb[j], 0.f);
    }
    __syncthreads();

    // mm2: 64 rows x 256 cols, K=32; tx2=tid&31 (4+4 cols), ty2=tid>>5 (8 rows)
    const int tx2 = tid & 31;
    const int ty2 = tid >> 5;
    float acc2[2][8][4] = {};
    #pragma unroll 8
    for (int k = 0; k < 32; ++k) {
        float b0[4], b1[4], a[8];
        *(float4*)&b0[0] = *(const float4*)(W1t + (size_t)k * 256 + tx2 * 4);
        *(float4*)&b1[0] = *(const float4*)(W1t + (size_t)k * 256 + 128 + tx2 * 4);
        *(float4*)&a[0] = *(const float4*)&T1[k][ty2 * 8];
        *(float4*)&a[4] = *(const float4*)&T1[k][ty2 * 8 + 4];
        #pragma unroll
        for (int i = 0; i < 8; ++i)
            #pragma unroll
            for (int j = 0; j < 4; ++j) {
                acc2[0][i][j] = fmaf(a[i], b0[j], acc2[0][i][j]);
                acc2[1][i][j] = fmaf(a[i], b1[j], acc2[1][i][j]);
            }
    }
    {
        float bb0[4], bb1[4];
        *(float4*)&bb0[0] = *(const float4*)(B1 + tx2 * 4);
        *(float4*)&bb1[0] = *(const float4*)(B1 + 128 + tx2 * 4);
        #pragma unroll
        for (int i = 0; i < 8; ++i) {
            const int row = ty2 * 8 + i;
            const size_t gr = (size_t)(r0 + row) * 256;
            float4 h0 = *(const float4*)&Hr[row][tx2 * 4];
            float4 h1 = *(const float4*)&Hr[row][128 + tx2 * 4];
            float4 v0, v1;
            v0.x = h0.x + acc2[0][i][0] + bb0[0];
            v0.y = h0.y + acc2[0][i][1] + bb0[1];
            v0.z = h0.z + acc2[0][i][2] + bb0[2];
            v0.w = h0.w + acc2[0][i][3] + bb0[3];
            v1.x = h1.x + acc2[1][i][0] + bb1[0];
            v1.y = h1.y + acc2[1][i][1] + bb1[1];
            v1.z = h1.z + acc2[1][i][2] + bb1[2];
            v1.w = h1.w + acc2[1][i][3] + bb1[3];
            *(float4*)(H + gr + tx2 * 4)       = v0;
            *(float4*)(H + gr + 128 + tx2 * 4) = v1;
        }
    }
}

// ---------------- full-width GEMM, W register-prefetch pipeline ------------
template <int K, int OC, bool PRE_RELU, bool POST_RELU>
__global__ __launch_bounds__(256)
void gemmf_k(const float* __restrict__ X, const float* __restrict__ Wt,
             const float* __restrict__ Bv, float* __restrict__ Y)
{
    constexpr int KH  = (K < 128) ? K : 128;      // staged K-half
    constexpr int SW  = KH + 4;                   // padded row stride (16B-aligned)
    constexpr int TX  = (OC == 256) ? 32 : 16;
    constexpr int TYN = 256 / TX;                 // # ty groups
    constexpr int RP  = 64 / TYN;                 // rows per thread
    constexpr int NCH = (OC > TX * 4) ? 2 : 1;    // col chunks
    constexpr int CHW = OC / NCH;                 // chunk width

    __shared__ float S[64 * SW];

    const int tid = threadIdx.x;
    const int r0  = blockIdx.x * 64;
    const int tx  = tid & (TX - 1);
    const int ty  = tid / TX;

    float acc[NCH][RP][4] = {};
    float4 bA[4][NCH], bB[4][NCH];

#define LOADW(dst, kb)                                                        \
    {                                                                         \
        _Pragma("unroll")                                                     \
        for (int kk = 0; kk < 4; ++kk)                                        \
            _Pragma("unroll")                                                 \
            for (int c = 0; c < NCH; ++c)                                     \
                dst[kk][c] = *(const float4*)(Wt + (size_t)((kb) + kk) * OC   \
                                              + c * CHW + tx * 4);            \
    }

#define COMPQ(bsrc, kl)                                                       \
    {                                                                         \
        float a4[RP][4];                                                      \
        _Pragma("unroll")                                                     \
        for (int i = 0; i < RP; ++i)                                          \
            *(float4*)&a4[i][0] = *(const float4*)&S[(ty * RP + i) * SW + (kl)]; \
        _Pragma("unroll")                                                     \
        for (int kk = 0; kk < 4; ++kk)                                        \
            _Pragma("unroll")                                                 \
            for (int c = 0; c < NCH; ++c) {                                   \
                const float* bp = (const float*)&bsrc[kk][c];                 \
                _Pragma("unroll")                                             \
                for (int i = 0; i < RP; ++i)                                  \
                    _Pragma("unroll")                                         \
                    for (int j = 0; j < 4; ++j)                               \
                        acc[c][i][j] = fmaf(a4[i][kk], bp[j], acc[c][i][j]);  \
            }                                                                 \
    }

    LOADW(bA, 0);                                 // prologue: first quad

    for (int h = 0; h < K; h += KH) {
        // stage 64 x KH (coalesced float4; optional relu)
        #pragma unroll
        for (int it = 0; it < (64 * KH / 4) / 256; ++it) {
            int idx = tid + it * 256;
            int m = idx / (KH / 4), g = idx % (KH / 4);
            float4 v = *(const float4*)(X + (size_t)(r0 + m) * K + h + g * 4);
            if (PRE_RELU) {
                v.x = fmaxf(v.x, 0.f); v.y = fmaxf(v.y, 0.f);
                v.z = fmaxf(v.z, 0.f); v.w = fmaxf(v.w, 0.f);
            }
            *(float4*)&S[m * SW + g * 4] = v;
        }
        __syncthreads();

        for (int k8 = 0; k8 < KH; k8 += 8) {
            LOADW(bB, h + k8 + 4);                // prefetch quad 2
            COMPQ(bA, k8);
            const int kn = (h + k8 + 8 < K) ? (h + k8 + 8) : 0;  // next quad (or dummy)
            LOADW(bA, kn);                        // prefetch quad 1 of next pair/half
            COMPQ(bB, k8 + 4);
        }
        __syncthreads();
    }
#undef LOADW
#undef COMPQ

    #pragma unroll
    for (int c = 0; c < NCH; ++c) {
        float bb[4];
        *(float4*)&bb[0] = *(const float4*)(Bv + c * CHW + tx * 4);
        #pragma unroll
        for (int i = 0; i < RP; ++i) {
            float4 v;
            v.x = acc[c][i][0] + bb[0];
            v.y = acc[c][i][1] + bb[1];
            v.z = acc[c][i][2] + bb[2];
            v.w = acc[c][i][3] + bb[3];
            if (POST_RELU) {
                v.x = fmaxf(v.x, 0.f); v.y = fmaxf(v.y, 0.f);
                v.z = fmaxf(v.z, 0.f); v.w = fmaxf(v.w, 0.f);
            }
            *(float4*)(Y + (size_t)(r0 + ty * RP + i) * OC + c * CHW + tx * 4) = v;
        }
    }
}

// ---------------- standalone GEMM (used only for d2, O=165) ---------------
template <bool PRE_RELU, bool POST_RELU, int YM>
__global__ __launch_bounds__(256)
void gemm_k(const float* __restrict__ X, const float* __restrict__ Wt,
            const float* __restrict__ Bv, void* __restrict__ Y,
            int K, int O, const int* __restrict__ dtf)
{
    __shared__ float Xs[32][132];
    __shared__ float Ws[32][68];

    const bool f32d = (YM == 1) ? (*dtf != 0) : false;
    const int tid = threadIdx.x;
    const int tx  = tid & 15;
    const int ty  = tid >> 4;
    const int o0  = blockIdx.x * 64;
    const int m0  = blockIdx.y * 128;

    float acc[8][4] = {};
    const int KC = K >> 5;                       // K multiple of 32
    for (int kc = 0; kc < KC; ++kc) {
        const int k0 = kc << 5;
        #pragma unroll
        for (int it = 0; it < 4; ++it) {         // X: 128 x 32 as float4
            int idx = tid + it * 256;
            int kq = idx & 7, m = idx >> 3;
            float4 v = *(const float4*)(X + (size_t)(m0 + m) * K + k0 + kq * 4);
            if (PRE_RELU) {
                v.x = fmaxf(v.x, 0.f); v.y = fmaxf(v.y, 0.f);
                v.z = fmaxf(v.z, 0.f); v.w = fmaxf(v.w, 0.f);
            }
            Xs[kq * 4 + 0][m] = v.x; Xs[kq * 4 + 1][m] = v.y;
            Xs[kq * 4 + 2][m] = v.z; Xs[kq * 4 + 3][m] = v.w;
        }
        #pragma unroll
        for (int it = 0; it < 8; ++it) {
            int e = tid + it * 256;
            int kk = e & 31, o = e >> 5;
            int og = o0 + o;
            Ws[kk][o] = (og < O) ? Wt[(size_t)(k0 + kk) * O + og] : 0.f;
        }
        __syncthreads();
        #pragma unroll
        for (int kk = 0; kk < 32; ++kk) {
            float a[8], b[4];
            *(float4*)&a[0] = *(const float4*)&Xs[kk][ty * 8];
            *(float4*)&a[4] = *(const float4*)&Xs[kk][ty * 8 + 4];
            *(float4*)&b[0] = *(const float4*)&Ws[kk][tx * 4];
            #pragma unroll
            for (int i = 0; i < 8; ++i)
                #pragma unroll
                for (int j = 0; j < 4; ++j)
                    acc[i][j] = fmaf(a[i], b[j], acc[i][j]);
        }
        __syncthreads();
    }

    #pragma unroll
    for (int j = 0; j < 4; ++j) {
        int c = o0 + tx * 4 + j;
        if (c >= O) continue;
        float bb = Bv[c];
        #pragma unroll
        for (int i = 0; i < 8; ++i) {
            int r = m0 + ty * 8 + i;
            float v = acc[i][j] + bb;
            if (POST_RELU) v = fmaxf(v, 0.f);
            size_t yi = (size_t)r * O + c;
            if (YM == 0)   ((float*)Y)[yi] = v;
            else if (f32d) ((float*)Y)[yi] = v;
            else           ((__hip_bfloat16*)Y)[yi] = __float2bfloat16(v);
        }
    }
}

// ---------------- codebook prep --------------------------------------------
__global__ void prep_k(const float* __restrict__ E, float* __restrict__ Et)
{
    int idx = blockIdx.x * 256 + threadIdx.x;   // E is [64][512]
    Et[(idx & 511) * EDIM + (idx >> 9)] = E[idx];
}

__global__ void e2_k(const float* __restrict__ Et, float* __restrict__ e2)
{
    int e = blockIdx.x * 256 + threadIdx.x;
    float s = 0.f;
    #pragma unroll
    for (int d = 0; d < EDIM; ++d) { float v = Et[e * EDIM + d]; s = fmaf(v, v, s); }
    e2[e] = s;
}

// ---------------- decoder-conv0 table: D0tab[e][o] = Et[e]@Wd0t[:,o]+b -----
__global__ void d0tab_k(const float* __restrict__ Et, const float* __restrict__ Wd0t,
                        const float* __restrict__ Bd0, float* __restrict__ D0tab)
{
    const int e = blockIdx.x;        // 512 codes
    const int o = threadIdx.x;       // 256 outputs
    float s = Bd0[o];
    #pragma unroll
    for (int d = 0; d < EDIM; ++d)
        s = fmaf(Et[e * EDIM + d], Wd0t[(size_t)d * 256 + o], s);
    D0tab[(size_t)e * 256 + o] = s;
}

// ---------------- VQ: GEMM-argmin + direct D0tab gather into A1 ------------
__global__ __launch_bounds__(256)
void vq_k(const float* __restrict__ Zq, const float* __restrict__ Ed,
          const float* __restrict__ Et, const float* __restrict__ e2,
          const float* __restrict__ D0tab, float* __restrict__ A1,
          float* __restrict__ acc)
{
    __shared__ float Zs[64][132];    // [d][row], 128 rows + pad
    __shared__ float Es[64][68];     // [d][code] chunk of 64 codes

    const int tid = threadIdx.x;
    const int tx  = tid & 15;        // code group (4 codes)
    const int ty  = tid >> 4;        // row group (8 rows)
    const int r0  = blockIdx.x * 128;

    // stage Z tile k-major
    #pragma unroll
    for (int it = 0; it < 8; ++it) {
        int idx = tid + it * 256;                // 128 rows x 16 float4
        int dq = idx & 15, m = idx >> 4;
        float4 v = *(const float4*)(Zq + (size_t)(r0 + m) * 64 + dq * 4);
        Zs[dq * 4 + 0][m] = v.x; Zs[dq * 4 + 1][m] = v.y;
        Zs[dq * 4 + 2][m] = v.z; Zs[dq * 4 + 3][m] = v.w;
    }

    float best[8];
    int   bi[8];
    #pragma unroll
    for (int i = 0; i < 8; ++i) { best[i] = 3.4e38f; bi[i] = 0; }

    for (int cc = 0; cc < 8; ++cc) {
        const int c0 = cc * 64;
        #pragma unroll
        for (int it = 0; it < 4; ++it) {
            int idx = tid + it * 256;            // 64 k x 16 float4
            int oq = idx & 15, kk = idx >> 4;
            *(float4*)&Es[kk][oq * 4] =
                *(const float4*)(Ed + (size_t)kk * NEMB + c0 + oq * 4);
        }
        float4 e2v = *(const float4*)(e2 + c0 + tx * 4);
        __syncthreads();

        float a4[8][4] = {};
        #pragma unroll 8
        for (int kk = 0; kk < 64; ++kk) {
            float a[8], b[4];
            *(float4*)&a[0] = *(const float4*)&Zs[kk][ty * 8];
            *(float4*)&a[4] = *(const float4*)&Zs[kk][ty * 8 + 4];
            *(float4*)&b[0] = *(const float4*)&Es[kk][tx * 4];
            #pragma unroll
            for (int i = 0; i < 8; ++i)
                #pragma unroll
                for (int j = 0; j < 4; ++j)
                    a4[i][j] = fmaf(a[i], b[j], a4[i][j]);
        }

        const float e2a[4] = {e2v.x, e2v.y, e2v.z, e2v.w};
        #pragma unroll
        for (int j = 0; j < 4; ++j) {
            const int code = c0 + tx * 4 + j;    // visited in increasing order
            #pragma unroll
            for (int i = 0; i < 8; ++i) {
                float s = fmaf(-2.f, a4[i][j], e2a[j]);
                if (s < best[i]) { best[i] = s; bi[i] = code; }  // strict <: first-min
            }
        }
        __syncthreads();
    }

    // argmin reduce over the 16 lanes sharing each row (tie-break low index)
    #pragma unroll
    for (int i = 0; i < 8; ++i) {
        #pragma unroll
        for (int m = 1; m < 16; m <<= 1) {
            float ob = __shfl_xor(best[i], m);
            int   oi = __shfl_xor(bi[i], m);
            if (ob < best[i] || (ob == best[i] && oi < bi[i])) {
                best[i] = ob; bi[i] = oi;
            }
        }
    }

    // diff accumulation (Zq re-read is L2-hot) + gather decoder-conv0 row
    // from D0tab (L2-resident 512KB) directly into A1. No Zq writeback.
    float ds = 0.f;
    #pragma unroll
    for (int i = 0; i < 8; ++i) {
        const int row = r0 + ty * 8 + i;
        float4 qv = *(const float4*)(Et + (size_t)bi[i] * 64 + tx * 4);
        float4 zv = *(const float4*)(Zq + (size_t)row * 64 + tx * 4);
        float t;
        t = qv.x - zv.x; ds = fmaf(t, t, ds);
        t = qv.y - zv.y; ds = fmaf(t, t, ds);
        t = qv.z - zv.z; ds = fmaf(t, t, ds);
        t = qv.w - zv.w; ds = fmaf(t, t, ds);

        const float* src = D0tab + (size_t)bi[i] * 256 + tx * 16;
        float* dst = A1 + (size_t)row * 256 + tx * 16;
        #pragma unroll
        for (int q = 0; q < 4; ++q)
            *(float4*)(dst + q * 4) = *(const float4*)(src + q * 4);
    }
    #pragma unroll
    for (int off = 32; off; off >>= 1) ds += __shfl_down(ds, off);
    if ((tid & 63) == 0) atomicAdd(acc, ds);
}

__global__ void diff_k(const float* __restrict__ acc, void* __restrict__ out,
                       size_t off, const int* __restrict__ dtf)
{
    if (threadIdx.x == 0) {
        float v = *acc * (1.0f / 8388608.0f);
        if (*dtf) ((float*)out)[off] = v;
        else      ((__hip_bfloat16*)out)[off] = __float2bfloat16(v);
    }
}

// ---------------------------------------------------------------------------
extern "C" void kernel_launch(void* const* d_in, const int* in_sizes, int n_in,
                              void* d_out, int out_size, void* d_ws, size_t ws_size,
                              hipStream_t stream)
{
    const size_t MB = 1048576;
    char* ws = (char*)d_ws;
    float* Zq  = (float*)ws;                                  // N x 64
    float* A1  = (float*)(ws + 32 * MB);                      // N x 256
    float* A2  = (float*)(ws + 32 * MB + 128 * MB);           // N x 256
    float* Wf  = (float*)(ws + 288 * MB);                     // fp32 weights
    float* Et  = (float*)(ws + 288 * MB + 1310720);           // 512 x 64
    float* e2  = Et + NEMB * EDIM;
    float* acc = e2 + NEMB;
    int*   dtf = (int*)(acc + 1);
    float* D0t = (float*)(ws + 296 * MB);                     // 512 x 256 table

    // weight table (K-major transpose for 2-D weights)
    static const int KDIM[32] = {0, 165,0, 128,0, 256,0, 256,0, 32,0, 256,0, 32,0,
                                 256,0, 0, 64,0, 256,0, 32,0, 256,0, 32,0, 256,0, 128,0};
    WTbl t;
    int off[32];
    int cum = 0;
    for (int i = 1; i < 32; ++i) {
        t.p[i - 1]   = d_in[i];
        t.off[i - 1] = cum;
        t.n[i - 1]   = in_sizes[i];
        t.Kd[i - 1]  = KDIM[i];
        off[i] = cum;
        cum += in_sizes[i];
    }
    const float* W_ew0 = Wf + off[1],  *B_ew0 = Wf + off[2];
    const float* W_ew1 = Wf + off[3],  *B_ew1 = Wf + off[4];
    const float* W_ew2 = Wf + off[5],  *B_ew2 = Wf + off[6];
    const float* W_r0a = Wf + off[7],  *B_r0a = Wf + off[8];
    const float* W_r0b = Wf + off[9],  *B_r0b = Wf + off[10];
    const float* W_r1a = Wf + off[11], *B_r1a = Wf + off[12];
    const float* W_r1b = Wf + off[13], *B_r1b = Wf + off[14];
    const float* W_qc  = Wf + off[15], *B_qc  = Wf + off[16];
    const float* Emb   = Wf + off[17];
    const float* W_d0  = Wf + off[18], *B_d0  = Wf + off[19];
    const float* W_s0a = Wf + off[20], *B_s0a = Wf + off[21];
    const float* W_s0b = Wf + off[22], *B_s0b = Wf + off[23];
    const float* W_s1a = Wf + off[24], *B_s1a = Wf + off[25];
    const float* W_s1b = Wf + off[26], *B_s1b = Wf + off[27];
    const float* W_d1  = Wf + off[28], *B_d1  = Wf + off[29];
    const float* W_d2  = Wf + off[30], *B_d2  = Wf + off[31];

    dim3 blk(256);
    const int NB = NTOT / 64;          // 2048 row blocks

    detect_k<<<1, blk, 0, stream>>>(d_in[0], dtf, acc);
    convw_k<<<31, blk, 0, stream>>>(t, Wf, dtf);
    prep_k<<<128, blk, 0, stream>>>(Emb, Et);
    e2_k<<<2, blk, 0, stream>>>(Et, e2);
    d0tab_k<<<NEMB, blk, 0, stream>>>(Et, W_d0, B_d0, D0t);

    // ---- encoder ----
    enc01_k<<<NB, blk, 0, stream>>>(d_in[0], W_ew0, B_ew0, W_ew1, B_ew1, A1, dtf);
    gemmf_k<256, 256, false, false><<<NB, blk, 0, stream>>>(A1, W_ew2, B_ew2, A2);
    res_k<<<NB, blk, 0, stream>>>(A2, W_r0a, B_r0a, W_r0b, B_r0b);
    res_k<<<NB, blk, 0, stream>>>(A2, W_r1a, B_r1a, W_r1b, B_r1b);
    gemmf_k<256, 64, true, false><<<NB, blk, 0, stream>>>(A2, W_qc, B_qc, Zq);

    // ---- VQ (argmin + diff + fused decoder-conv0 gather into A1) ----
    vq_k<<<NTOT / 128, blk, 0, stream>>>(Zq, Emb, Et, e2, D0t, A1, acc);

    // ---- decoder (d0 GEMM eliminated; A1 already holds conv0 output) ----
    res_k<<<NB, blk, 0, stream>>>(A1, W_s0a, B_s0a, W_s0b, B_s0b);
    res_k<<<NB, blk, 0, stream>>>(A1, W_s1a, B_s1a, W_s1b, B_s1b);
    gemmf_k<256, 128, true, true><<<NB, blk, 0, stream>>>(A1, W_d1, B_d1, A2);
    gemm_k<false, false, 1><<<dim3(3, NTOT / 128), blk, 0, stream>>>
        (A2, W_d2, B_d2, d_out, 128, 165, dtf);

    diff_k<<<1, 64, 0, stream>>>(acc, d_out, (size_t)NTOT * 165, dtf);
}